// Round 11
// baseline (214.691 us; speedup 1.0000x reference)
//
#include <hip/hip_runtime.h>

#define N_NODES 100000
#define N_EDGES 1250000
#define IN_D 128
#define OUT_D 64
#define BSHIFT 7                                  // 128 nodes per bucket
#define NBUCK  782                                // ceil(100000/128)
#define CAP    2600                               // mean 1600 + 25 sigma
#define EPB    2048                               // edges per passA block
#define NBLK_E 611                                // ceil(1250000/2048)
#define NBLK_G 1563                               // ceil(6250 node-tiles / 4)

typedef __attribute__((ext_vector_type(8))) __bf16 bf16x8;
typedef __attribute__((ext_vector_type(4))) float floatx4;

__device__ __forceinline__ float2 up2(unsigned u) {   // 2 bf16 -> 2 f32
    return make_float2(__uint_as_float(u << 16),
                       __uint_as_float(u & 0xFFFF0000u));
}

// ---- Kernel A (fused): blocks [0,611): passA bucket scatter (int4 MLP,
//      fixed-capacity buckets, payload {src|(d&127)<<17, tc*edge_d}).
//      blocks [611,...): node_proj MFMA GEMM, conflict-free W swizzle. ----
__global__ __launch_bounds__(256) void fusedA_kernel(
    const float* __restrict__ x, const float* __restrict__ W1,
    const float* __restrict__ W2, const float* __restrict__ W0,
    const float* __restrict__ Wa,
    const int* __restrict__ dst, const int* __restrict__ src,
    const float* __restrict__ edge_d,
    int* __restrict__ gcur, uint2* __restrict__ payA,
    unsigned short* __restrict__ zb, unsigned short* __restrict__ zib,
    float* __restrict__ s1, float* __restrict__ s2)
{
    __shared__ __bf16 sB[16384];     // 32 KB (GEMM path)
    __shared__ float  sWa[128];
    __shared__ int    h[NBUCK];      // passA path (3.1 KB)
    __shared__ int    lcur[NBUCK];

    const int t = threadIdx.x;

    if (blockIdx.x < NBLK_E) {
        // ---------------- passA ----------------
        const float tc = W0[0] * Wa[2 * OUT_D];
        for (int i = t; i < NBUCK; i += 256) h[i] = 0;
        __syncthreads();
        const int base = blockIdx.x * EPB;
        for (int k0 = 0; k0 < EPB; k0 += 1024) {
            int i = base + k0 + t * 4;
            if (i < N_EDGES) {                    // N_EDGES % 4 == 0
                int4 d4 = *(const int4*)(dst + i);
                atomicAdd(&h[d4.x >> BSHIFT], 1);
                atomicAdd(&h[d4.y >> BSHIFT], 1);
                atomicAdd(&h[d4.z >> BSHIFT], 1);
                atomicAdd(&h[d4.w >> BSHIFT], 1);
            }
        }
        __syncthreads();
        for (int b = t; b < NBUCK; b += 256) {
            int hc = h[b];
            int p = hc ? atomicAdd(&gcur[b], hc) : 0;
            lcur[b] = b * CAP + p;
        }
        __syncthreads();
        #define EMIT(dv, sv, ev)                                              \
            { int bk = (dv) >> BSHIFT;                                        \
              int pos = atomicAdd(&lcur[bk], 1);                              \
              if (pos < (bk + 1) * CAP)                                       \
                  payA[pos] = make_uint2((unsigned)(sv) |                     \
                                         ((unsigned)((dv) & 127) << 17),      \
                                         __float_as_uint(tc * (ev))); }
        for (int k0 = 0; k0 < EPB; k0 += 1024) {
            int i = base + k0 + t * 4;
            if (i < N_EDGES) {
                int4   d4 = *(const int4*)(dst + i);
                int4   s4 = *(const int4*)(src + i);
                float4 e4 = *(const float4*)(edge_d + i);
                EMIT(d4.x, s4.x, e4.x);
                EMIT(d4.y, s4.y, e4.y);
                EMIT(d4.z, s4.z, e4.z);
                EMIT(d4.w, s4.w, e4.w);
            }
        }
        #undef EMIT
        return;
    }

    // ------- node_proj: conflict-free W swizzle -------
    // idx = t + g*256 IS the linear 16B fragment slot: decompose
    // idx = ((nt*4+kc)*4 + kb)*16 + m; element = W'[n=nt*16+m][k=(kc*4+kb)*8+j].
    // Consecutive threads -> consecutive 16B LDS writes (no bank conflict).
    #pragma unroll
    for (int g = 0; g < 8; ++g) {
        int idx = t + g * 256;           // 0..2047
        int m  = idx & 15;
        int kb = (idx >> 4) & 3;
        int kc = (idx >> 6) & 3;
        int nt = idx >> 8;
        int n  = nt * 16 + m;
        int k8 = kc * 4 + kb;
        const float* wrow = (n < 64) ? (W1 + n * 128) : (W2 + (n - 64) * 128);
        float4 v0 = *(const float4*)(wrow + k8 * 8);
        float4 v1 = *(const float4*)(wrow + k8 * 8 + 4);
        bf16x8 bb;
        bb[0] = (__bf16)v0.x; bb[1] = (__bf16)v0.y;
        bb[2] = (__bf16)v0.z; bb[3] = (__bf16)v0.w;
        bb[4] = (__bf16)v1.x; bb[5] = (__bf16)v1.y;
        bb[6] = (__bf16)v1.z; bb[7] = (__bf16)v1.w;
        *(bf16x8*)(sB + idx * 8) = bb;
    }
    if (t < 128) sWa[t] = Wa[t];
    __syncthreads();

    const int lane = t & 63;
    const int wave = t >> 6;
    const int tile = (blockIdx.x - NBLK_E) * 4 + wave;
    if (tile * 16 >= N_NODES) return;          // 100000 % 16 == 0

    const int n0 = tile * 16;
    const int m  = lane & 15;
    const int kb = lane >> 4;

    floatx4 acc[8];
    #pragma unroll
    for (int q = 0; q < 8; ++q) acc[q] = (floatx4)(0.f);

    const float* xrow = x + (size_t)(n0 + m) * IN_D;

    #pragma unroll
    for (int kc = 0; kc < 4; ++kc) {
        float4 v0 = *(const float4*)(xrow + kc * 32 + kb * 8);
        float4 v1 = *(const float4*)(xrow + kc * 32 + kb * 8 + 4);
        float xs[8] = {v0.x, v0.y, v0.z, v0.w, v1.x, v1.y, v1.z, v1.w};
        bf16x8 ahi, alo;
        #pragma unroll
        for (int j = 0; j < 8; ++j) {
            __bf16 hh = (__bf16)xs[j];
            ahi[j] = hh;
            alo[j] = (__bf16)(xs[j] - (float)hh);
        }
        #pragma unroll
        for (int nt = 0; nt < 8; ++nt) {
            int off = ((nt * 4 + kc) * 64 + lane) * 8;
            bf16x8 b = *(const bf16x8*)(sB + off);
            acc[nt] = __builtin_amdgcn_mfma_f32_16x16x32_bf16(ahi, b, acc[nt], 0, 0, 0);
            acc[nt] = __builtin_amdgcn_mfma_f32_16x16x32_bf16(alo, b, acc[nt], 0, 0, 0);
        }
    }

    // D layout: col = lane&15 (=m), row = kb*4 + reg
    #pragma unroll
    for (int nt = 0; nt < 8; ++nt) {
        int col = (nt & 3) * 16 + m;
        unsigned short* dp = (nt < 4) ? zb : zib;
        #pragma unroll
        for (int reg = 0; reg < 4; ++reg) {
            int row = n0 + kb * 4 + reg;
            __bf16 hh = (__bf16)acc[nt][reg];
            dp[(size_t)row * OUT_D + col] = *(unsigned short*)&hh;
        }
    }

    // s1[n] = z[n,:].Wa[0:64], s2[n] = z[n,:].Wa[64:128]  (fp32 accs)
    #pragma unroll
    for (int reg = 0; reg < 4; ++reg) {
        float p1 = 0.f, p2 = 0.f;
        #pragma unroll
        for (int nt = 0; nt < 4; ++nt) {
            float zv = acc[nt][reg];
            p1 += zv * sWa[nt * 16 + m];
            p2 += zv * sWa[64 + nt * 16 + m];
        }
        #pragma unroll
        for (int off = 8; off > 0; off >>= 1) {
            p1 += __shfl_xor(p1, off);
            p2 += __shfl_xor(p2, off);
        }
        if (m == 0) {
            int row = n0 + kb * 4 + reg;
            s1[row] = p1;
            s2[row] = p2;
        }
    }
}

// ---- Kernel B (bucket_gather): one block per 128-node bucket. Hist, scan,
//      permute payload INTO LDS, then gather+softmax+finalize for its nodes.
//      8 half-wave node slots x 16 rounds; s1-gather + exp computed in place
//      in the LDS queue; z weighted-sum via 4 edge slots x 8 chunk lanes. ----
__global__ __launch_bounds__(256) void bucket_gather_kernel(
    const int* __restrict__ gcur, const uint2* __restrict__ payA,
    const float* __restrict__ s1, const float* __restrict__ s2,
    const unsigned short* __restrict__ zb, const unsigned short* __restrict__ zib,
    float* __restrict__ out)
{
    __shared__ uint2 buf[CAP];       // 20.8 KB bucket payload
    __shared__ int h[128], st[128], lc[128], sm[128];

    const int b = blockIdx.x, t = threadIdx.x;
    const int base = b * CAP;
    const int cnt = min(gcur[b], CAP);
    const int n0 = b << BSHIFT;

    if (t < 128) h[t] = 0;
    __syncthreads();
    for (int i0 = t * 2; i0 < cnt; i0 += 512) {
        uint4 u = *(const uint4*)(payA + base + i0);   // CAP % 4 == 0
        atomicAdd(&h[(u.x >> 17) & 127], 1);
        if (i0 + 1 < cnt) atomicAdd(&h[(u.z >> 17) & 127], 1);
    }
    __syncthreads();

    if (t < 128) sm[t] = h[t];
    __syncthreads();
    for (int off = 1; off < 128; off <<= 1) {
        int add = 0;
        if (t < 128 && t >= off) add = sm[t - off];
        __syncthreads();
        if (t < 128) sm[t] += add;
        __syncthreads();
    }
    if (t < 128) { int s_ = sm[t] - h[t]; st[t] = s_; lc[t] = s_; }
    __syncthreads();

    for (int i0 = t * 2; i0 < cnt; i0 += 512) {
        uint4 u = *(const uint4*)(payA + base + i0);
        int j0 = (u.x >> 17) & 127;
        int p0 = atomicAdd(&lc[j0], 1);
        buf[p0] = make_uint2(u.x & 0x1FFFFu, u.y);
        if (i0 + 1 < cnt) {
            int j1 = (u.z >> 17) & 127;
            int p1 = atomicAdd(&lc[j1], 1);
            buf[p1] = make_uint2(u.z & 0x1FFFFu, u.w);
        }
    }
    __syncthreads();

    // ---------------- gather/finalize ----------------
    const int slot = t >> 5;          // node slot (0..7)
    const int lh   = t & 31;
    const int eC   = lh >> 3;         // edge slot (0..3)
    const int c    = lh & 7;          // feature chunk

    for (int j = slot; j < 128; j += 8) {
        int d = n0 + j;
        if (d >= N_NODES) break;
        const int beg = st[j];
        const int len = h[j];
        const float s2d = s2[d];

        float den = 0.f;
        float2 a0 = make_float2(0.f, 0.f), a1 = a0, a2 = a0, a3 = a0;

        for (int o = 0; o < len; o += 32) {
            int rem = len - o;
            if (lh < rem) {
                uint2 p = buf[beg + o + lh];
                float a = __uint_as_float(p.y) + s1[p.x] + s2d;
                float e = (a > 0.f) ? a : 0.01f * a;
                float ex = __expf(e);
                den += ex;
                buf[beg + o + lh].y = __float_as_uint(ex);
            }
            // same-wave LDS write->read: hardware-ordered
            int cc = min(32, rem);
            for (int g = 0; g * 4 < cc; ++g) {
                int j2 = g * 4 + eC;
                uint2 pe = buf[beg + o + ((j2 < cc) ? j2 : 0)];
                float exe = (j2 < cc) ? __uint_as_float(pe.y) : 0.f;
                uint4 zv = *(const uint4*)(zb + (size_t)pe.x * OUT_D + c * 8);
                float2 w0 = up2(zv.x), w1 = up2(zv.y), w2 = up2(zv.z), w3 = up2(zv.w);
                a0.x = fmaf(exe, w0.x, a0.x); a0.y = fmaf(exe, w0.y, a0.y);
                a1.x = fmaf(exe, w1.x, a1.x); a1.y = fmaf(exe, w1.y, a1.y);
                a2.x = fmaf(exe, w2.x, a2.x); a2.y = fmaf(exe, w2.y, a2.y);
                a3.x = fmaf(exe, w3.x, a3.x); a3.y = fmaf(exe, w3.y, a3.y);
            }
        }

        #pragma unroll
        for (int off = 16; off > 0; off >>= 1) den += __shfl_xor(den, off);
        #pragma unroll
        for (int off = 8; off <= 16; off <<= 1) {
            a0.x += __shfl_xor(a0.x, off); a0.y += __shfl_xor(a0.y, off);
            a1.x += __shfl_xor(a1.x, off); a1.y += __shfl_xor(a1.y, off);
            a2.x += __shfl_xor(a2.x, off); a2.y += __shfl_xor(a2.y, off);
            a3.x += __shfl_xor(a3.x, off); a3.y += __shfl_xor(a3.y, off);
        }

        if (lh < 8) {
            float inv = (den > 0.f) ? 1.f / den : 0.f;   // empty -> relu(zi)
            uint4 zv = *(const uint4*)(zib + (size_t)d * OUT_D + lh * 8);
            float2 w0 = up2(zv.x), w1 = up2(zv.y), w2 = up2(zv.z), w3 = up2(zv.w);
            float4 o0, o1;
            o0.x = fmaxf(w0.x + a0.x * inv, 0.f);
            o0.y = fmaxf(w0.y + a0.y * inv, 0.f);
            o0.z = fmaxf(w1.x + a1.x * inv, 0.f);
            o0.w = fmaxf(w1.y + a1.y * inv, 0.f);
            o1.x = fmaxf(w2.x + a2.x * inv, 0.f);
            o1.y = fmaxf(w2.y + a2.y * inv, 0.f);
            o1.z = fmaxf(w3.x + a3.x * inv, 0.f);
            o1.w = fmaxf(w3.y + a3.y * inv, 0.f);
            *(float4*)(out + (size_t)d * OUT_D + lh * 8)     = o0;
            *(float4*)(out + (size_t)d * OUT_D + lh * 8 + 4) = o1;
        }
    }
}

extern "C" void kernel_launch(void* const* d_in, const int* in_sizes, int n_in,
                              void* d_out, int out_size, void* d_ws, size_t ws_size,
                              hipStream_t stream) {
    const float* node_feats = (const float*)d_in[0];
    const float* edge_d     = (const float*)d_in[1];
    const float* W0         = (const float*)d_in[2];
    const float* W1         = (const float*)d_in[3];
    const float* W2         = (const float*)d_in[4];
    const float* Wa         = (const float*)d_in[5];
    const int*   src        = (const int*)d_in[6];
    const int*   dst        = (const int*)d_in[7];
    float* out = (float*)d_out;

    // workspace layout (~43 MB), 16 B aligned sections
    char* ws = (char*)d_ws;
    uint2* payA = (uint2*)ws;    ws += (size_t)NBUCK * CAP * 8;   // 16.3 MB
    unsigned short* zbuf = (unsigned short*)ws; ws += (size_t)N_NODES * OUT_D * 2;
    unsigned short* zib  = (unsigned short*)ws; ws += (size_t)N_NODES * OUT_D * 2;
    float* s1 = (float*)ws;      ws += (size_t)N_NODES * 4;
    float* s2 = (float*)ws;      ws += (size_t)N_NODES * 4;
    int*   gcur = (int*)ws;      ws += ((NBUCK + 3) & ~3) * 4;

    hipMemsetAsync(gcur, 0, NBUCK * 4, stream);

    fusedA_kernel<<<NBLK_E + NBLK_G, 256, 0, stream>>>(
        node_feats, W1, W2, W0, Wa, dst, src, edge_d,
        gcur, payA, zbuf, zib, s1, s2);

    bucket_gather_kernel<<<NBUCK, 256, 0, stream>>>(
        gcur, payA, s1, s2, zbuf, zib, out);
}